// Round 7
// baseline (650.815 us; speedup 1.0000x reference)
//
#include <hip/hip_runtime.h>
#include <math.h>

#define EMB 128
#define MID 192
#define SEQ 128
#define BATCH 16
#define NPAIR 127
#define KCLS 5
#define EPSF 1e-5f

// ws float-offsets
#define OFF_WBIG  0                      // 768*128 (col j contiguous: WBIG[j*128+k])
#define OFF_BY    98304                  // 128
#define OFF_BXX2  98432                  // 256   bxx2 = bxx + Wxx^T by
#define OFF_WY    98688                  // 256*128 plain Wy[k][o] (temp)
#define OFF_WXX   131456                 // 128*256 plain Wxx[k][c] (temp)
#define OFF_BXX   164224                 // 256 (temp)
#define OFF_NODES 164480                 // B*128*128
#define OFF_L0    426624                 // B*127
#define OFF_L     428656                 // B*128*128  L[b][slot][d]
#define OFF_R     690800                 // B*128*128
#define OFF_UL    952944                 // B*128*256  UL[b][slot][c]
#define OFF_UR    1477232                // B*128*256
// end 2001520 floats (~8 MB)

// ---- k_comp1: plain composites Wy/Wxx/biases + WBIG cols 0-255 + node gather
__global__ void k_comp1(const float* __restrict__ W1, const float* __restrict__ b1,
                        const float* __restrict__ W2, const float* __restrict__ b2,
                        const float* __restrict__ W3, const float* __restrict__ b3,
                        const float* __restrict__ W4, const float* __restrict__ b4,
                        const int* __restrict__ inp, const float* __restrict__ emb,
                        float* __restrict__ ws) {
    int tid = blockIdx.x * blockDim.x + threadIdx.x;
    if (tid < 32768) {                    // Wy[k][o], k<256, o<128
        int k = tid >> 7, o = tid & 127;
        float a = 0.f;
        for (int j = 0; j < MID; ++j) a += W1[k*MID+j] * W2[j*EMB+o];
        ws[OFF_WY + k*128 + o] = a;
        // WBIG col o (L-part, left weights k>=128) / col 128+o (R-part)
        if (k >= 128) ws[OFF_WBIG + o*128 + (k-128)] = a;
        else          ws[OFF_WBIG + (128+o)*128 + k] = a;
    } else if (tid < 65536) {             // Wxx[k][c], k<128, c<256
        int t = tid - 32768;
        int k = t >> 8, c = t & 255;
        float a = 0.f;
        for (int j = 0; j < MID; ++j) a += W3[k*MID+j] * W4[j*256+c];
        ws[OFF_WXX + k*256 + c] = a;
    } else if (tid < 65664) {             // by
        int o = tid - 65536;
        float a = b2[o];
        for (int j = 0; j < MID; ++j) a += b1[j] * W2[j*EMB+o];
        ws[OFF_BY + o] = a;
    } else if (tid < 65920) {             // bxx (temp)
        int o = tid - 65664;
        float a = b4[o];
        for (int j = 0; j < MID; ++j) a += b3[j] * W4[j*256+o];
        ws[OFF_BXX + o] = a;
    } else if (tid < 65920 + BATCH*SEQ*EMB) {  // node gather
        int t2 = tid - 65920;
        int d = t2 & 127, bs = t2 >> 7;
        int tok = inp[bs];
        ws[OFF_NODES + t2] = emb[tok*EMB + d];
    }
}

// ---- k_comp2: WBIG cols 256-767 (W_LX, W_RX) + bxx2 -----------------------
__global__ void k_comp2(float* __restrict__ ws) {
    int tid = blockIdx.x * blockDim.x + threadIdx.x;
    if (tid < 32768) {                    // W_LX[k][c] = sum_m Wy[128+k][m]*Wxx[m][c]
        int k = tid >> 8, c = tid & 255;
        float a = 0.f;
        for (int m = 0; m < 128; ++m) a += ws[OFF_WY + (128+k)*128 + m] * ws[OFF_WXX + m*256 + c];
        ws[OFF_WBIG + (256+c)*128 + k] = a;
    } else if (tid < 65536) {             // W_RX[k][c] = sum_m Wy[k][m]*Wxx[m][c]
        int t = tid - 32768;
        int k = t >> 8, c = t & 255;
        float a = 0.f;
        for (int m = 0; m < 128; ++m) a += ws[OFF_WY + k*128 + m] * ws[OFF_WXX + m*256 + c];
        ws[OFF_WBIG + (512+c)*128 + k] = a;
    } else if (tid < 65792) {             // bxx2[c]
        int c = tid - 65536;
        float a = ws[OFF_BXX + c];
        for (int m = 0; m < 128; ++m) a += ws[OFF_BY + m] * ws[OFF_WXX + m*256 + c];
        ws[OFF_BXX2 + c] = a;
    }
}

// ---- k_cache: per-node L/R/UL/UR for all 128 leaves, 16 rows x 16 groups ---
__global__ void __launch_bounds__(768) k_cache(float* __restrict__ ws) {
    __shared__ float s_x[EMB];
    int tid = threadIdx.x;
    int b = blockIdx.x >> 4, g = blockIdx.x & 15;
    float4 wb[32];
    {
        const float4* gw = (const float4*)(ws + OFF_WBIG) + (size_t)tid*32;
        #pragma unroll
        for (int i = 0; i < 32; ++i) wb[i] = gw[i];
    }
    const float* gnod = ws + OFF_NODES + (size_t)b*SEQ*EMB;
    float* gL  = ws + OFF_L  + (size_t)b*SEQ*EMB;
    float* gR  = ws + OFF_R  + (size_t)b*SEQ*EMB;
    float* gUL = ws + OFF_UL + (size_t)b*SEQ*256;
    float* gUR = ws + OFF_UR + (size_t)b*SEQ*256;
    for (int i = 0; i < 8; ++i) {
        int n = g*8 + i;
        if (tid < EMB) s_x[tid] = gnod[n*EMB + tid];
        __syncthreads();
        float a0=0.f,a1=0.f,a2=0.f,a3=0.f;
        const float4* f4 = (const float4*)s_x;
        #pragma unroll
        for (int ii = 0; ii < 8; ++ii) {
            float4 w0 = wb[4*ii+0], x0 = f4[4*ii+0];
            float4 w1 = wb[4*ii+1], x1 = f4[4*ii+1];
            float4 w2 = wb[4*ii+2], x2 = f4[4*ii+2];
            float4 w3 = wb[4*ii+3], x3 = f4[4*ii+3];
            a0 += w0.x*x0.x + w0.y*x0.y + w0.z*x0.z + w0.w*x0.w;
            a1 += w1.x*x1.x + w1.y*x1.y + w1.z*x1.z + w1.w*x1.w;
            a2 += w2.x*x2.x + w2.y*x2.y + w2.z*x2.z + w2.w*x2.w;
            a3 += w3.x*x3.x + w3.y*x3.y + w3.z*x3.z + w3.w*x3.w;
        }
        float o = (a0+a1)+(a2+a3);
        if      (tid < 128) gL [n*EMB + tid]        = o;
        else if (tid < 256) gR [n*EMB + tid-128]    = o;
        else if (tid < 512) gUL[n*256 + tid-256]    = o;
        else                gUR[n*256 + tid-512]    = o;
        __syncthreads();
    }
}

// ---- k_loss: initial 127 pair losses from UL/UR ---------------------------
__global__ void __launch_bounds__(128) k_loss(float* __restrict__ ws) {
    __shared__ float s_ls[2];
    int tid = threadIdx.x;
    int b = blockIdx.x / NPAIR, j = blockIdx.x % NPAIR;
    int h2 = tid >> 6, lane = tid & 63;
    const float* gUL = ws + OFF_UL + (size_t)b*SEQ*256;
    const float* gUR = ws + OFF_UR + (size_t)b*SEQ*256;
    const float* gnod = ws + OFF_NODES + (size_t)b*SEQ*EMB;
    int cA = h2*128 + lane, cB = cA + 64;
    float v0 = gUL[j*256+cA] + gUR[(j+1)*256+cA] + ws[OFF_BXX2+cA];
    float v1 = gUL[j*256+cB] + gUR[(j+1)*256+cB] + ws[OFF_BXX2+cB];
    float m = fmaxf(v0, v1);
    for (int s = 32; s; s >>= 1) m = fmaxf(m, __shfl_xor(m, s, 64));
    float se = expf(v0 - m) + expf(v1 - m);
    for (int s = 32; s; s >>= 1) se += __shfl_xor(se, s, 64);
    float lse = m + logf(se);
    int slotD = j + (h2 == 0 ? 1 : 0);
    float o0 = gnod[slotD*EMB + lane];
    float o1 = gnod[slotD*EMB + 64 + lane];
    float term = o0*(v0 - lse) + o1*(v1 - lse);
    for (int s = 32; s; s >>= 1) term += __shfl_xor(term, s, 64);
    if (lane == 0) s_ls[h2] = -term;
    __syncthreads();
    if (tid == 0) {
        float l = ((1.f+EPSF)*s_ls[0] + (1.f+EPSF)*s_ls[1]) / (2.f + EPSF);
        ws[OFF_L0 + b*NPAIR + j] = l;
    }
}

// ---- k_seq: one block (768 thr) per row; 4 barriers/step -------------------
__global__ void __launch_bounds__(768) k_seq(float* __restrict__ ws,
                      const float* __restrict__ Wk, const float* __restrict__ bkv,
                      float* __restrict__ out) {
    __shared__ float s_nodes[SEQ*EMB];    // 64 KB
    __shared__ float s_father[EMB];
    __shared__ float s_Lf[EMB];
    __shared__ float s_Rf[EMB];
    __shared__ float s_ULf[256];
    __shared__ float s_URf[256];
    __shared__ float s_by[EMB];
    __shared__ float s_bxx2[256];
    __shared__ float s_ls[2][2];
    __shared__ float s_loss[2][NPAIR];
    __shared__ float s_cnt[2][SEQ];
    __shared__ int   s_nslot[2][SEQ];
    __shared__ int   s_q[2];
    __shared__ int   s_sFb[2];
    __shared__ float s_wv[2];
    __shared__ int   s_wi[2];
    __shared__ float s_log[KCLS];

    int tid = threadIdx.x;
    int b = blockIdx.x;
    float4 wb[32];
    {
        const float4* gw = (const float4*)(ws + OFF_WBIG) + (size_t)tid*32;
        #pragma unroll
        for (int i = 0; i < 32; ++i) wb[i] = gw[i];
    }
    float* gnod = ws + OFF_NODES + (size_t)b*SEQ*EMB;
    float* gL  = ws + OFF_L  + (size_t)b*SEQ*EMB;
    float* gR  = ws + OFF_R  + (size_t)b*SEQ*EMB;
    float* gUL = ws + OFF_UL + (size_t)b*SEQ*256;
    float* gUR = ws + OFF_UR + (size_t)b*SEQ*256;
    {
        const float4* gn4 = (const float4*)gnod;
        float4* sn = (float4*)s_nodes;
        for (int i = tid; i < SEQ*EMB/4; i += 768) sn[i] = gn4[i];
    }
    if (tid < EMB) s_by[tid] = ws[OFF_BY + tid];
    if (tid < 256) s_bxx2[tid] = ws[OFF_BXX2 + tid];
    if (tid < NPAIR) s_loss[0][tid] = ws[OFF_L0 + b*NPAIR + tid];
    if (tid < SEQ) { s_cnt[0][tid] = 1.f; s_nslot[0][tid] = tid; }
    if (tid == 0) { s_sFb[0] = -1; s_sFb[1] = -1; }
    float acc = 0.f;
    __syncthreads();

    #pragma unroll 1
    for (int t = 0; t < NPAIR; ++t) {
        int L = SEQ - t;
        int cur = t & 1;
        int prevPar = (t + 1) & 1;        // parity written by F(t-1)
        int sF = s_sFb[prevPar];
        if (t > 0) {
            {   // ---- M: father -> [L_f | R_f | UL_f | UR_f], 128->768 matvec
                float a0=0.f,a1=0.f,a2=0.f,a3=0.f;
                const float4* f4 = (const float4*)s_father;
                #pragma unroll
                for (int ii = 0; ii < 8; ++ii) {
                    float4 w0 = wb[4*ii+0], x0 = f4[4*ii+0];
                    float4 w1 = wb[4*ii+1], x1 = f4[4*ii+1];
                    float4 w2 = wb[4*ii+2], x2 = f4[4*ii+2];
                    float4 w3 = wb[4*ii+3], x3 = f4[4*ii+3];
                    a0 += w0.x*x0.x + w0.y*x0.y + w0.z*x0.z + w0.w*x0.w;
                    a1 += w1.x*x1.x + w1.y*x1.y + w1.z*x1.z + w1.w*x1.w;
                    a2 += w2.x*x2.x + w2.y*x2.y + w2.z*x2.z + w2.w*x2.w;
                    a3 += w3.x*x3.x + w3.y*x3.y + w3.z*x3.z + w3.w*x3.w;
                }
                float o = (a0+a1)+(a2+a3);
                if      (tid < 128) { gL [sF*EMB + tid]      = o; s_Lf [tid]     = o; }
                else if (tid < 256) { gR [sF*EMB + tid-128]  = o; s_Rf [tid-128] = o; }
                else if (tid < 512) { gUL[sF*256 + tid-256]  = o; s_ULf[tid-256] = o; }
                else                { gUR[sF*256 + tid-512]  = o; s_URf[tid-512] = o; }
            }
            __syncthreads();                                   // bar1
            if (tid < 256) {   // ---- D': xx via cache adds + softmax + loss
                int w = tid >> 6, lane = tid & 63;
                int p2 = w >> 1, h2 = w & 1;
                int q = s_q[p2];
                int slotL = s_nslot[cur][q], slotR = s_nslot[cur][q+1];
                int cA = h2*128 + lane, cB = cA + 64;
                float ulA = (slotL == sF) ? s_ULf[cA] : gUL[slotL*256 + cA];
                float ulB = (slotL == sF) ? s_ULf[cB] : gUL[slotL*256 + cB];
                float urA = (slotR == sF) ? s_URf[cA] : gUR[slotR*256 + cA];
                float urB = (slotR == sF) ? s_URf[cB] : gUR[slotR*256 + cB];
                float v0 = ulA + urA + s_bxx2[cA];
                float v1 = ulB + urB + s_bxx2[cB];
                float m = fmaxf(v0, v1);
                for (int s = 32; s; s >>= 1) m = fmaxf(m, __shfl_xor(m, s, 64));
                float se = expf(v0 - m) + expf(v1 - m);
                for (int s = 32; s; s >>= 1) se += __shfl_xor(se, s, 64);
                float lse = m + logf(se);
                int slotD = (h2 == 0) ? slotR : slotL;
                float o0 = s_nodes[slotD*EMB + lane];
                float o1 = s_nodes[slotD*EMB + 64 + lane];
                float term = o0*(v0 - lse) + o1*(v1 - lse);
                for (int s = 32; s; s >>= 1) term += __shfl_xor(term, s, 64);
                if (lane == 0) s_ls[p2][h2] = -term;
            }
            __syncthreads();                                   // bar2
        }
        // ---- E: fused loss-update + argmin (first-occurrence ties)
        if (tid < 128) {
            float v = INFINITY;
            if (tid < L-1) {
                v = s_loss[cur][tid];
                if (t > 0 && (tid == s_q[0] || tid == s_q[1])) {
                    int which = (tid == s_q[0]) ? 0 : 1;
                    float n1 = s_cnt[cur][tid+1], n2 = s_cnt[cur][tid];
                    v = ((n1+EPSF)*s_ls[which][0] + (n2+EPSF)*s_ls[which][1]) / (n1+n2+EPSF);
                    s_loss[cur][tid] = v;   // own-slot write
                }
            }
            int ii = tid;
            for (int s = 32; s; s >>= 1) {
                float ov = __shfl_xor(v, s, 64);
                int   oi = __shfl_xor(ii, s, 64);
                if (ov < v || (ov == v && oi < ii)) { v = ov; ii = oi; }
            }
            if ((tid & 63) == 0) { s_wv[tid>>6] = v; s_wi[tid>>6] = ii; }
        }
        __syncthreads();                                       // bar3
        // ---- F: select + merge bookkeeping + father from L/R caches
        {
            float bv0 = s_wv[0], bv1 = s_wv[1];
            int idx = (bv1 < bv0) ? s_wi[1] : s_wi[0];
            if (tid == 0) acc += fminf(bv0, bv1);
            int pos = idx > 0 ? idx - 1 : 0;
            int nxt = cur ^ 1;
            bool doShift = (idx > 0);
            if (tid < 128) {
                int sC = (doShift && tid >= pos+1 && tid <= L-2) ? 1 : 0;
                float nc = s_cnt[cur][tid + sC];
                int   nn = s_nslot[cur][tid + sC];
                if (tid == pos) nc = s_cnt[cur][idx] + s_cnt[cur][idx == 0 ? L-1 : idx-1];
                s_cnt[nxt][tid] = nc;
                s_nslot[nxt][tid] = nn;
                if (tid < NPAIR) {
                    int sL = (doShift && tid >= pos+1 && tid <= L-3) ? 1 : 0;
                    s_loss[nxt][tid] = s_loss[cur][tid + sL];
                }
            } else if (tid < 256) {
                int d = tid - 128;
                int slotI  = s_nslot[cur][idx];
                int slotI1 = s_nslot[cur][idx+1];
                int slotF  = s_nslot[cur][pos];
                float fL = (slotI  == sF) ? s_Lf[d] : gL[slotI*EMB + d];
                float fR = (slotI1 == sF) ? s_Rf[d] : gR[slotI1*EMB + d];
                float fa = fL + fR + s_by[d];
                s_father[d] = fa;
                s_nodes[slotF*EMB + d] = fa;
            } else if (tid == 256) {
                s_q[0] = (pos >= 1) ? pos - 1 : pos;
                s_q[1] = pos;
                s_sFb[t & 1] = s_nslot[cur][pos];
            }
        }
        __syncthreads();                                       // bar4
    }
    // prediction from final root node (final state buffer = 1)
    if (tid < KCLS) {
        int slot0 = s_nslot[1][0];
        float a = bkv[tid];
        for (int k = 0; k < EMB; ++k) a += s_nodes[slot0*EMB + k] * Wk[k*KCLS + tid];
        s_log[tid] = a;
    }
    __syncthreads();
    if (tid == 0) {
        int best = 0;
        for (int cc = 1; cc < KCLS; ++cc) if (s_log[cc] > s_log[best]) best = cc;
        out[b] = (float)best;
        atomicAdd(&out[BATCH], acc * (1.f/16.f));
    }
}

extern "C" void kernel_launch(void* const* d_in, const int* in_sizes, int n_in,
                              void* d_out, int out_size, void* d_ws, size_t ws_size,
                              hipStream_t stream) {
    const int*   inp = (const int*)d_in[0];
    const float* emb = (const float*)d_in[1];
    const float* W1  = (const float*)d_in[2];
    const float* b1  = (const float*)d_in[3];
    const float* W2  = (const float*)d_in[4];
    const float* b2  = (const float*)d_in[5];
    const float* W3  = (const float*)d_in[6];
    const float* b3  = (const float*)d_in[7];
    const float* W4  = (const float*)d_in[8];
    const float* b4  = (const float*)d_in[9];
    const float* Wk  = (const float*)d_in[10];
    const float* bk  = (const float*)d_in[11];
    float* out = (float*)d_out;
    float* ws  = (float*)d_ws;

    hipMemsetAsync(d_out, 0, (size_t)out_size * sizeof(float), stream);

    int n1 = 65920 + BATCH*SEQ*EMB;
    k_comp1<<<(n1 + 255) / 256, 256, 0, stream>>>(W1, b1, W2, b2, W3, b3, W4, b4, inp, emb, ws);
    k_comp2<<<(65792 + 255) / 256, 256, 0, stream>>>(ws);
    k_cache<<<BATCH * 16, 768, 0, stream>>>(ws);
    k_loss<<<BATCH * NPAIR, 128, 0, stream>>>(ws);
    k_seq<<<BATCH, 768, 0, stream>>>(ws, Wk, bk, out);
}